// Round 14
// baseline (569.037 us; speedup 1.0000x reference)
//
#include <hip/hip_runtime.h>
#include <hip/hip_bf16.h>

#define DI __device__ __forceinline__

typedef short bf16x8 __attribute__((ext_vector_type(8)));
typedef float f32x4 __attribute__((ext_vector_type(4)));

typedef __attribute__((address_space(3))) unsigned lds_u32;
typedef __attribute__((address_space(1))) const unsigned g_u32;

DI void gload16(const void* g, void* lds) {
  __builtin_amdgcn_global_load_lds((g_u32*)g, (lds_u32*)lds, 16, 0, 0);
}

DI unsigned short bf16bits(float f) {
  __hip_bfloat16 h = __float2bfloat16(f);
  return *(unsigned short*)&h;
}

// Compact tanh-form GELU, register-pressure-minimal (~13 VALU, 3-4 temps).
DI float gelu_fast(float v) {
  const float v2 = v * v;
  const float u = v * __builtin_fmaf(0.0356774081f, v2, 0.7978845608f);
  const float a = fabsf(u);
  const float e2 = __expf(-2.0f * a);
  const float r = __builtin_amdgcn_rcpf(1.0f + e2);
  float t = __builtin_fmaf(-2.0f * e2, r, 1.0f);
  t = copysignf(t, u);
  const float h = 0.5f * v;
  return __builtin_fmaf(h, t, h);
}

// ---------------------------------------------------------------------------
// prep_kernel: all six weight transposes + RoPE tables in ONE dispatch.
// ---------------------------------------------------------------------------
__global__ __launch_bounds__(256)
void prep_kernel(const float* __restrict__ wq, const float* __restrict__ wk,
                 const float* __restrict__ wv, const float* __restrict__ wo,
                 const float* __restrict__ w1, const float* __restrict__ w2,
                 __hip_bfloat16* __restrict__ wt_qkv,
                 __hip_bfloat16* __restrict__ wt_wo,
                 __hip_bfloat16* __restrict__ wt_w1,
                 __hip_bfloat16* __restrict__ wt_w2,
                 float* __restrict__ cost, float* __restrict__ sint) {
  const int idx = blockIdx.x;
  if (idx >= 12288) {
    const int e = (idx - 12288) * 4 + (threadIdx.x >> 6);  // s: 0..575
    const int d = threadIdx.x & 63;
    const int j = d >> 1;
    const float pos = (j < 16) ? (float)(e % 24) * (1.0f / 3.0f)
                               : (float)(e / 24) * (1.0f / 3.0f);
    const int fi = j & 15;
    const float freq = powf(10000.0f, -(float)fi * (1.0f / 16.0f));
    const float a = pos * freq;
    cost[e * 64 + d] = cosf(a);
    sint[e * 64 + d] = sinf(a);
    return;
  }
  const float* w;
  __hip_bfloat16* wt;
  int K, N, tile;
  if (idx < 4096) {
    const int seg = idx >> 10;  // 0..3 : wq,wk,wv,wo
    tile = idx & 1023;
    K = 1024; N = 1024;
    w = (seg == 0) ? wq : (seg == 1) ? wk : (seg == 2) ? wv : wo;
    wt = (seg < 3) ? (wt_qkv + (size_t)seg * 1024 * 1024) : wt_wo;
  } else if (idx < 8192) {
    tile = idx - 4096; K = 1024; N = 4096; w = w1; wt = wt_w1;
  } else {
    tile = idx - 8192; K = 4096; N = 1024; w = w2; wt = wt_w2;
  }
  const int ntx = N >> 5;
  const int nb = (tile % ntx) * 32, kb = (tile / ntx) * 32;
  __shared__ float tilebuf[32][33];
  const int tx = threadIdx.x & 31, ty = threadIdx.x >> 5;  // 32 x 8
#pragma unroll
  for (int i = 0; i < 4; ++i)
    tilebuf[ty + i * 8][tx] = w[(size_t)(kb + ty + i * 8) * N + nb + tx];
  __syncthreads();
#pragma unroll
  for (int i = 0; i < 4; ++i)
    wt[(size_t)(nb + ty + i * 8) * K + kb + tx] = __float2bfloat16(tilebuf[tx][ty + i * 8]);
}

// ---------------------------------------------------------------------------
// LayerNorm: fp32 in -> bf16 out, one block per token (1024 ch, 256 thr x 4)
// ---------------------------------------------------------------------------
__global__ __launch_bounds__(256)
void ln_kernel(const float* __restrict__ in, const float* __restrict__ g,
               const float* __restrict__ b, __hip_bfloat16* __restrict__ out) {
  const int t = blockIdx.x, tid = threadIdx.x;
  const float4 x = *(const float4*)(in + (size_t)t * 1024 + tid * 4);
  float s = x.x + x.y + x.z + x.w;
  float sq = x.x * x.x + x.y * x.y + x.z * x.z + x.w * x.w;
#pragma unroll
  for (int off = 32; off >= 1; off >>= 1) {
    s += __shfl_down(s, off);
    sq += __shfl_down(sq, off);
  }
  __shared__ float red[8];
  const int wave = tid >> 6, lane = tid & 63;
  if (lane == 0) { red[wave] = s; red[4 + wave] = sq; }
  __syncthreads();
  s = red[0] + red[1] + red[2] + red[3];
  sq = red[4] + red[5] + red[6] + red[7];
  const float mean = s * (1.0f / 1024.0f);
  const float var = sq * (1.0f / 1024.0f) - mean * mean;
  const float rstd = rsqrtf(var + 1e-6f);
  const int c = tid * 4;
  const float4 gg = *(const float4*)(g + c);
  const float4 bb = *(const float4*)(b + c);
  ushort4 o;
  o.x = bf16bits((x.x - mean) * rstd * gg.x + bb.x);
  o.y = bf16bits((x.y - mean) * rstd * gg.y + bb.y);
  o.z = bf16bits((x.z - mean) * rstd * gg.z + bb.z);
  o.w = bf16bits((x.w - mean) * rstd * gg.w + bb.w);
  *(ushort4*)((unsigned short*)out + (size_t)t * 1024 + c) = o;
}

// ---------------------------------------------------------------------------
// GEMM: C[M,N] = A[M,K] @ Bt[N,K]^T, bf16 inputs, fp32 accum.
// 128x128 tile, BK=64, 256 threads (4 waves, 2x2 of 64x64), 16x16x32 MFMA.
// r12 core EXACT (84 VGPR; conflict-free granule-XOR LDS; column-grouped +
// XCD raster; gelu_fast + fences in MODE 1).
// NEW: SPLITK template param. SPLITK=2 (MODE 2 only): blockIdx.z selects a
// K-half; per-block tile/efficiency unchanged, block count doubles (the
// variable r13's MIB=2 test confounded). Accumulation via f32 atomicAdd
// (device-scope); bias added by the z=0 slice only.
// MODE 0: out bf16 = acc + bias
// MODE 1: out bf16 = gelu(acc + bias)
// MODE 2: out f32 += acc + bias      (atomicAdd when SPLITK>1)
// MODE 3: window-unpartition row perm; out f32[t] = resid[t] + acc + bias
// ---------------------------------------------------------------------------
template<int MODE, int SPLITK>
__global__ __launch_bounds__(256)
void gemm_bt_kernel(const __hip_bfloat16* __restrict__ A,
                    const __hip_bfloat16* __restrict__ Bt,
                    const float* __restrict__ bias,
                    void* __restrict__ out,
                    const float* __restrict__ resid,
                    int M, int N, int K) {
  __shared__ __hip_bfloat16 As[128 * 64];
  __shared__ __hip_bfloat16 Bs[128 * 64];
  const int tid = threadIdx.x;
  const int wave = tid >> 6, lane = tid & 63;
  const int lr = lane & 15, lg = lane >> 4;
  // bijective XCD swizzle (m204) over the (x,y) slice; z-slices share the
  // same (bm,bn) mapping (same panels -> same-XCD locality is desirable).
  const unsigned nwg = gridDim.x * gridDim.y;
  const unsigned bid0 = blockIdx.y * gridDim.x + blockIdx.x;
  const unsigned xcd = bid0 & 7u, idx = bid0 >> 3;
  const unsigned q8 = nwg >> 3, r8 = nwg & 7u;
  const unsigned L = (xcd < r8 ? xcd * (q8 + 1u)
                               : r8 * (q8 + 1u) + (xcd - r8) * q8) + idx;
  // column-grouped raster: groups of 8 N-tiles, row-major within a group
  const unsigned gpr = gridDim.y * 8u;          // blocks per column-group
  const unsigned grp = L / gpr, rr = L - grp * gpr;
  const int bm = (int)(rr >> 3) * 128;
  const int bn = (int)(grp * 8u + (rr & 7u)) * 128;
  const int wr = (wave >> 1) * 64, wc = (wave & 1) * 64;
  const int srow = lane >> 3;                       // 0..7 (LDS row mod 8)
  const int scol = ((lane & 7) ^ srow) * 8;         // pre-swizzled source col
  const int rsw = lr & 7;                           // read-side XOR key

  f32x4 acc[4][4] = {};

  const int Kh = K / SPLITK;
  const int kz = (SPLITK > 1) ? blockIdx.z : 0;
  const int kbeg = kz * Kh, kend = kbeg + Kh;

  for (int k0 = kbeg; k0 < kend; k0 += 64) {
#pragma unroll
    for (int c = 0; c < 4; ++c) {
      const int ch = wave * 4 + c;
      gload16(A + (size_t)(bm + ch * 8 + srow) * K + k0 + scol, &As[ch * 512]);
      gload16(Bt + (size_t)(bn + ch * 8 + srow) * K + k0 + scol, &Bs[ch * 512]);
    }
    __syncthreads();
#pragma unroll
    for (int kk = 0; kk < 64; kk += 32) {
      const int kg = kk >> 3;  // granule base: 0 or 4
      bf16x8 af[4], bfr[4];
#pragma unroll
      for (int i = 0; i < 4; ++i)
        af[i] = *(const bf16x8*)&As[(wr + i * 16 + lr) * 64 + (((kg + lg) ^ rsw) * 8)];
#pragma unroll
      for (int i = 0; i < 4; ++i)
        bfr[i] = *(const bf16x8*)&Bs[(wc + i * 16 + lr) * 64 + (((kg + lg) ^ rsw) * 8)];
#pragma unroll
      for (int mi = 0; mi < 4; ++mi)
#pragma unroll
        for (int ni = 0; ni < 4; ++ni)
          acc[mi][ni] = __builtin_amdgcn_mfma_f32_16x16x32_bf16(af[mi], bfr[ni],
                                                                acc[mi][ni], 0, 0, 0);
    }
    __syncthreads();
  }

#pragma unroll
  for (int ni = 0; ni < 4; ++ni) {
    const int gn = bn + wc + ni * 16 + lr;
    const float bv = (bias && kz == 0) ? bias[gn] : 0.0f;
#pragma unroll
    for (int mi = 0; mi < 4; ++mi) {
      const int rowb = bm + wr + mi * 16 + lg * 4;
#pragma unroll
      for (int j = 0; j < 4; ++j) {
        const float v = acc[mi][ni][j] + bv;
        const int gm = rowb + j;
        if (MODE == 0) {
          ((__hip_bfloat16*)out)[(size_t)gm * N + gn] = __float2bfloat16(v);
        } else if (MODE == 1) {
          const float gl = gelu_fast(v);
          ((__hip_bfloat16*)out)[(size_t)gm * N + gn] = __float2bfloat16(gl);
          __builtin_amdgcn_sched_barrier(0);  // cap live ranges (r8 lesson)
        } else if (MODE == 2) {
          if (SPLITK > 1) {
            atomicAdd((float*)out + (size_t)gm * N + gn, v);
          } else {
            ((float*)out)[(size_t)gm * N + gn] += v;
          }
        } else {
          const int win = gm / 576, s = gm % 576;
          const int bb2 = win / 9, wi = (win % 9) / 3, wj = win % 3;
          const int t = (bb2 * 72 + wi * 24 + (s / 24)) * 72 + wj * 24 + (s % 24);
          ((float*)out)[(size_t)t * 1024 + gn] =
              resid[(size_t)t * 1024 + gn] + v;
        }
      }
    }
  }
}

// ---------------------------------------------------------------------------
// ropev: RoPE+bias+window scatter for Q/K (blocks x<576) AND V bias+window
// gather+transpose (blocks x>=576, head = x-576) in one dispatch.
// ---------------------------------------------------------------------------
__global__ __launch_bounds__(256)
void ropev_kernel(const __hip_bfloat16* __restrict__ qkvraw,
                  const float* __restrict__ bq, const float* __restrict__ bk,
                  const float* __restrict__ bv,
                  const float* __restrict__ cost, const float* __restrict__ sint,
                  __hip_bfloat16* __restrict__ qw, __hip_bfloat16* __restrict__ kw,
                  __hip_bfloat16* __restrict__ vt) {
  __shared__ __hip_bfloat16 tile[64][72];
  const int win = blockIdx.y;  // 0..17
  const int b = win / 9, wi = (win % 9) / 3, wj = win % 3;
  const int tid = threadIdx.x;
  if (blockIdx.x < 576) {
    const int s = blockIdx.x;
    const int t = (b * 72 + wi * 24 + (s / 24)) * 72 + wj * 24 + (s % 24);
    const int col = tid * 4;           // 0..1020
    const int head = col >> 6, d = col & 63;
    const float c0 = cost[s * 64 + d + 0], c1 = cost[s * 64 + d + 1];
    const float c2 = cost[s * 64 + d + 2], c3 = cost[s * 64 + d + 3];
    const float s0 = sint[s * 64 + d + 0], s1 = sint[s * 64 + d + 1];
    const float s2 = sint[s * 64 + d + 2], s3 = sint[s * 64 + d + 3];
    const size_t rbase = (size_t)t * 3072;
    const size_t obase = (((size_t)(win * 16 + head)) * 576 + s) * 64 + d;
    {  // Q (fold softmax scale 1/8)
      const float q0 = __bfloat162float(qkvraw[rbase + col + 0]) + bq[col + 0];
      const float q1 = __bfloat162float(qkvraw[rbase + col + 1]) + bq[col + 1];
      const float q2 = __bfloat162float(qkvraw[rbase + col + 2]) + bq[col + 2];
      const float q3 = __bfloat162float(qkvraw[rbase + col + 3]) + bq[col + 3];
      ushort4 o;
      o.x = bf16bits(0.125f * (q0 * c0 - q1 * s0));
      o.y = bf16bits(0.125f * (q1 * c1 + q0 * s1));
      o.z = bf16bits(0.125f * (q2 * c2 - q3 * s2));
      o.w = bf16bits(0.125f * (q3 * c3 + q2 * s3));
      *(ushort4*)((unsigned short*)qw + obase) = o;
    }
    {  // K
      const float k0 = __bfloat162float(qkvraw[rbase + 1024 + col + 0]) + bk[col + 0];
      const float k1 = __bfloat162float(qkvraw[rbase + 1024 + col + 1]) + bk[col + 1];
      const float k2 = __bfloat162float(qkvraw[rbase + 1024 + col + 2]) + bk[col + 2];
      const float k3 = __bfloat162float(qkvraw[rbase + 1024 + col + 3]) + bk[col + 3];
      ushort4 o;
      o.x = bf16bits(k0 * c0 - k1 * s0);
      o.y = bf16bits(k1 * c1 + k0 * s1);
      o.z = bf16bits(k2 * c2 - k3 * s2);
      o.w = bf16bits(k3 * c3 + k2 * s3);
      *(ushort4*)((unsigned short*)kw + obase) = o;
    }
    return;
  }
  // V: bias + gather + transpose -> vt[win][head][d][s]
  const int head = blockIdx.x - 576;
  for (int s0 = 0; s0 < 576; s0 += 64) {
#pragma unroll
    for (int rep = 0; rep < 16; ++rep) {
      const int e = rep * 256 + tid;  // 0..4095
      const int si = e >> 6, d = e & 63;
      const int s = s0 + si;
      const int t = (b * 72 + wi * 24 + (s / 24)) * 72 + wj * 24 + (s % 24);
      const float v = __bfloat162float(qkvraw[(size_t)t * 3072 + 2048 + head * 64 + d])
                    + bv[head * 64 + d];
      tile[d][si] = __float2bfloat16(v);
    }
    __syncthreads();
#pragma unroll
    for (int rep = 0; rep < 16; ++rep) {
      const int e = rep * 256 + tid;
      const int d = e >> 6, si = e & 63;
      vt[((size_t)(win * 16 + head) * 64 + d) * 576 + s0 + si] = tile[d][si];
    }
    __syncthreads();
  }
}

// ---------------------------------------------------------------------------
// Flash attention per (qtile, head, win). 256 thr = 4 waves, 16 q-rows/wave.
// K/V LDS + Plds round-trip granule-XOR swizzled; T13 defer-max (r12 form).
// ---------------------------------------------------------------------------
__global__ __launch_bounds__(256)
void attn_kernel(const __hip_bfloat16* __restrict__ qw,
                 const __hip_bfloat16* __restrict__ kw,
                 const __hip_bfloat16* __restrict__ vt,
                 __hip_bfloat16* __restrict__ ow) {
  __shared__ __hip_bfloat16 Klds[2][64 * 64];
  __shared__ __hip_bfloat16 Vlds[2][64 * 64];
  __shared__ __hip_bfloat16 Plds[4 * 16 * 64];
  const unsigned nwg = gridDim.x * gridDim.y * gridDim.z;
  const unsigned bid0 = (blockIdx.z * gridDim.y + blockIdx.y) * gridDim.x + blockIdx.x;
  const unsigned Lw = (bid0 & 7u) * (nwg >> 3) + (bid0 >> 3);
  const int qt = (int)(Lw % 9u);          // 0..8
  const unsigned r = Lw / 9u;
  const int head = (int)(r & 15u);        // 0..15
  const int win = (int)(r >> 4);          // 0..17
  const int bh = win * 16 + head;
  const int tid = threadIdx.x, wave = tid >> 6, lane = tid & 63;
  const int lr = lane & 15, lg = lane >> 4;
  const int rsw = lr & 7;

  const int qrow = qt * 64 + wave * 16 + lr;
  const __hip_bfloat16* qbase = qw + ((size_t)bh * 576 + qrow) * 64;
  const bf16x8 q0 = *(const bf16x8*)(qbase + lg * 8);
  const bf16x8 q1 = *(const bf16x8*)(qbase + 32 + lg * 8);

  f32x4 oacc[4] = {};
  float mrow[4] = {-1e30f, -1e30f, -1e30f, -1e30f};
  float lrow[4] = {};

  const int srow = lane >> 3;
  const int sw = ((lane & 7) ^ srow) * 8;  // pre-swizzled source col

  auto stagekv = [&](int buf, int kv) {
#pragma unroll
    for (int c = 0; c < 2; ++c) {
      const int ch = wave * 2 + c;
      gload16(kw + ((size_t)bh * 576 + kv * 64 + ch * 8 + srow) * 64 + sw,
              &Klds[buf][ch * 512]);
      gload16(vt + ((size_t)bh * 64 + ch * 8 + srow) * 576 + kv * 64 + sw,
              &Vlds[buf][ch * 512]);
    }
  };

  stagekv(0, 0);
  __syncthreads();

  for (int kv = 0; kv < 9; ++kv) {
    const int cur = kv & 1;
    if (kv + 1 < 9) stagekv(cur ^ 1, kv + 1);
    __builtin_amdgcn_sched_barrier(0);

    f32x4 sfr[4];
    __builtin_amdgcn_s_setprio(1);
#pragma unroll
    for (int c = 0; c < 4; ++c) {
      const bf16x8 b0 = *(const bf16x8*)&Klds[cur][(c * 16 + lr) * 64 + ((lg ^ rsw) * 8)];
      const bf16x8 b1 = *(const bf16x8*)&Klds[cur][(c * 16 + lr) * 64 + (((4 + lg) ^ rsw) * 8)];
      f32x4 z = {};
      z = __builtin_amdgcn_mfma_f32_16x16x32_bf16(q0, b0, z, 0, 0, 0);
      z = __builtin_amdgcn_mfma_f32_16x16x32_bf16(q1, b1, z, 0, 0, 0);
      sfr[c] = z;
    }
    __builtin_amdgcn_s_setprio(0);

    // tile-max per row
    float mjv[4];
#pragma unroll
    for (int j = 0; j < 4; ++j) {
      float mj = fmaxf(fmaxf(sfr[0][j], sfr[1][j]), fmaxf(sfr[2][j], sfr[3][j]));
#pragma unroll
      for (int off = 1; off < 16; off <<= 1) mj = fmaxf(mj, __shfl_xor(mj, off));
      mjv[j] = mj;
    }
    // T13 defer-max: rescale only if some row grew past threshold
    bool defer = true;
#pragma unroll
    for (int j = 0; j < 4; ++j) defer = defer && (mjv[j] <= mrow[j] + 8.0f);
    if (!__all(defer)) {
#pragma unroll
      for (int j = 0; j < 4; ++j) {
        const float mn = fmaxf(mrow[j], mjv[j]);
        const float rs = __expf(mrow[j] - mn);
        mrow[j] = mn;
        lrow[j] *= rs;
#pragma unroll
        for (int d = 0; d < 4; ++d) oacc[d][j] *= rs;
      }
    }
    float p[4][4];
#pragma unroll
    for (int j = 0; j < 4; ++j) {
      float rs = 0.0f;
#pragma unroll
      for (int c = 0; c < 4; ++c) {
        const float pp = __expf(sfr[c][j] - mrow[j]);
        p[c][j] = pp;
        rs += pp;
      }
#pragma unroll
      for (int off = 1; off < 16; off <<= 1) rs += __shfl_xor(rs, off);
      lrow[j] += rs;
    }

    // P store (granule-XOR swizzled)
    {
      const int g0 = lr >> 3, c3 = lr & 7;
#pragma unroll
      for (int c = 0; c < 4; ++c)
#pragma unroll
        for (int j = 0; j < 4; ++j) {
          const int row = lg * 4 + j;
          const int g = (c * 2 + g0) ^ (row & 7);
          Plds[wave * 1024 + row * 64 + g * 8 + c3] = __float2bfloat16(p[c][j]);
        }
    }

    const bf16x8 pa0 = *(const bf16x8*)&Plds[wave * 1024 + lr * 64 + ((lg ^ rsw) * 8)];
    const bf16x8 pa1 = *(const bf16x8*)&Plds[wave * 1024 + lr * 64 + (((4 + lg) ^ rsw) * 8)];
    __builtin_amdgcn_s_setprio(1);
#pragma unroll
    for (int d = 0; d < 4; ++d) {
      const bf16x8 v0 = *(const bf16x8*)&Vlds[cur][(d * 16 + lr) * 64 + ((lg ^ rsw) * 8)];
      const bf16x8 v1 = *(const bf16x8*)&Vlds[cur][(d * 16 + lr) * 64 + (((4 + lg) ^ rsw) * 8)];
      oacc[d] = __builtin_amdgcn_mfma_f32_16x16x32_bf16(pa0, v0, oacc[d], 0, 0, 0);
      oacc[d] = __builtin_amdgcn_mfma_f32_16x16x32_bf16(pa1, v1, oacc[d], 0, 0, 0);
    }
    __builtin_amdgcn_s_setprio(0);
    __syncthreads();
  }

#pragma unroll
  for (int j = 0; j < 4; ++j) {
    const float inv = 1.0f / lrow[j];
    const int srow2 = qt * 64 + wave * 16 + lg * 4 + j;
    const size_t base = ((size_t)win * 576 + srow2) * 1024 + head * 64;
#pragma unroll
    for (int d = 0; d < 4; ++d)
      ow[base + d * 16 + lr] = __float2bfloat16(oacc[d][j] * inv);
  }
}

// ---------------------------------------------------------------------------
extern "C" void kernel_launch(void* const* d_in, const int* in_sizes, int n_in,
                              void* d_out, int out_size, void* d_ws, size_t ws_size,
                              hipStream_t stream) {
  const float* hidden = (const float*)d_in[0];
  const float* ln1_g = (const float*)d_in[1];
  const float* ln1_b = (const float*)d_in[2];
  const float* wq = (const float*)d_in[3];
  const float* bq = (const float*)d_in[4];
  const float* wk = (const float*)d_in[5];
  const float* bk = (const float*)d_in[6];
  const float* wv = (const float*)d_in[7];
  const float* bv = (const float*)d_in[8];
  const float* wo = (const float*)d_in[9];
  const float* bo = (const float*)d_in[10];
  const float* ln2_g = (const float*)d_in[11];
  const float* ln2_b = (const float*)d_in[12];
  const float* w1 = (const float*)d_in[13];
  const float* b1 = (const float*)d_in[14];
  const float* w2 = (const float*)d_in[15];
  const float* b2 = (const float*)d_in[16];
  float* out = (float*)d_out;

  char* p = (char*)d_ws;
  auto alloc = [&](size_t bytes) {
    char* r = p;
    p += (bytes + 255) & ~(size_t)255;
    return r;
  };
  __hip_bfloat16* wt_qkv = (__hip_bfloat16*)alloc(3072ull * 1024 * 2);
  __hip_bfloat16* wt_wo  = (__hip_bfloat16*)alloc(1024ull * 1024 * 2);
  __hip_bfloat16* wt_w1  = (__hip_bfloat16*)alloc(4096ull * 1024 * 2);
  __hip_bfloat16* wt_w2  = (__hip_bfloat16*)alloc(1024ull * 4096 * 2);
  float* cost = (float*)alloc(576ull * 64 * 4);
  float* sint = (float*)alloc(576ull * 64 * 4);
  __hip_bfloat16* xbuf = (__hip_bfloat16*)alloc(10368ull * 1024 * 2);  // xln / o_w / xln2
  char* big = alloc(10368ull * 4096 * 2);                              // qkvraw+qw | h1
  __hip_bfloat16* qkvraw = (__hip_bfloat16*)big;
  __hip_bfloat16* qw = (__hip_bfloat16*)(big + 10368ull * 3072 * 2);
  __hip_bfloat16* h1 = (__hip_bfloat16*)big;
  __hip_bfloat16* kw = (__hip_bfloat16*)alloc(18ull * 16 * 576 * 64 * 2);
  __hip_bfloat16* vt = (__hip_bfloat16*)alloc(18ull * 16 * 64 * 576 * 2);

  // weights -> bf16 transposed + RoPE tables (ONE dispatch)
  prep_kernel<<<12432, 256, 0, stream>>>(wq, wk, wv, wo, w1, w2,
                                         wt_qkv, wt_wo, wt_w1, wt_w2, cost, sint);
  // LN1 -> xln (bf16)
  ln_kernel<<<10368, 256, 0, stream>>>(hidden, ln1_g, ln1_b, xbuf);
  // QKV fused GEMM: [10368,1024] x [3072,1024]^T -> qkvraw bf16
  gemm_bt_kernel<0, 1><<<dim3(24, 81), 256, 0, stream>>>(
      xbuf, wt_qkv, nullptr, qkvraw, nullptr, 10368, 3072, 1024);
  // RoPE + window scatter (Q,K) and V transpose (ONE dispatch)
  ropev_kernel<<<dim3(592, 18), 256, 0, stream>>>(
      qkvraw, bq, bk, bv, cost, sint, qw, kw, vt);
  // attention -> o_w (windowed rows, [tw][1024]) into xbuf
  attn_kernel<<<dim3(9, 16, 18), 256, 0, stream>>>(qw, kw, vt, xbuf);
  // Wo GEMM + bias + residual + window-unpartition -> d_out (fp32 x)
  gemm_bt_kernel<3, 1><<<dim3(8, 81), 256, 0, stream>>>(
      xbuf, wt_wo, bo, out, hidden, 10368, 1024, 1024);
  // LN2 -> xln2 (bf16)
  ln_kernel<<<10368, 256, 0, stream>>>(out, ln2_g, ln2_b, xbuf);
  // MLP up + GELU -> h1 bf16
  gemm_bt_kernel<1, 1><<<dim3(32, 81), 256, 0, stream>>>(
      xbuf, wt_w1, b1, h1, nullptr, 10368, 4096, 1024);
  // MLP down, atomic += into d_out; split-K=2 (1296 blocks, 5/CU)
  gemm_bt_kernel<2, 2><<<dim3(8, 81, 2), 256, 0, stream>>>(
      h1, wt_w2, b2, out, nullptr, 10368, 1024, 4096);
}

// Round 15
// 549.514 us; speedup vs baseline: 1.0355x; 1.0355x over previous
//
#include <hip/hip_runtime.h>
#include <hip/hip_bf16.h>

#define DI __device__ __forceinline__

typedef short bf16x8 __attribute__((ext_vector_type(8)));
typedef float f32x4 __attribute__((ext_vector_type(4)));

typedef __attribute__((address_space(3))) unsigned lds_u32;
typedef __attribute__((address_space(1))) const unsigned g_u32;

DI void gload16(const void* g, void* lds) {
  __builtin_amdgcn_global_load_lds((g_u32*)g, (lds_u32*)lds, 16, 0, 0);
}

DI unsigned short bf16bits(float f) {
  __hip_bfloat16 h = __float2bfloat16(f);
  return *(unsigned short*)&h;
}

// Compact tanh-form GELU, register-pressure-minimal (~13 VALU, 3-4 temps).
DI float gelu_fast(float v) {
  const float v2 = v * v;
  const float u = v * __builtin_fmaf(0.0356774081f, v2, 0.7978845608f);
  const float a = fabsf(u);
  const float e2 = __expf(-2.0f * a);
  const float r = __builtin_amdgcn_rcpf(1.0f + e2);
  float t = __builtin_fmaf(-2.0f * e2, r, 1.0f);
  t = copysignf(t, u);
  const float h = 0.5f * v;
  return __builtin_fmaf(h, t, h);
}

// ---------------------------------------------------------------------------
// prep_kernel: all six weight transposes + RoPE tables in ONE dispatch.
// ---------------------------------------------------------------------------
__global__ __launch_bounds__(256)
void prep_kernel(const float* __restrict__ wq, const float* __restrict__ wk,
                 const float* __restrict__ wv, const float* __restrict__ wo,
                 const float* __restrict__ w1, const float* __restrict__ w2,
                 __hip_bfloat16* __restrict__ wt_qkv,
                 __hip_bfloat16* __restrict__ wt_wo,
                 __hip_bfloat16* __restrict__ wt_w1,
                 __hip_bfloat16* __restrict__ wt_w2,
                 float* __restrict__ cost, float* __restrict__ sint) {
  const int idx = blockIdx.x;
  if (idx >= 12288) {
    const int e = (idx - 12288) * 4 + (threadIdx.x >> 6);  // s: 0..575
    const int d = threadIdx.x & 63;
    const int j = d >> 1;
    const float pos = (j < 16) ? (float)(e % 24) * (1.0f / 3.0f)
                               : (float)(e / 24) * (1.0f / 3.0f);
    const int fi = j & 15;
    const float freq = powf(10000.0f, -(float)fi * (1.0f / 16.0f));
    const float a = pos * freq;
    cost[e * 64 + d] = cosf(a);
    sint[e * 64 + d] = sinf(a);
    return;
  }
  const float* w;
  __hip_bfloat16* wt;
  int K, N, tile;
  if (idx < 4096) {
    const int seg = idx >> 10;  // 0..3 : wq,wk,wv,wo
    tile = idx & 1023;
    K = 1024; N = 1024;
    w = (seg == 0) ? wq : (seg == 1) ? wk : (seg == 2) ? wv : wo;
    wt = (seg < 3) ? (wt_qkv + (size_t)seg * 1024 * 1024) : wt_wo;
  } else if (idx < 8192) {
    tile = idx - 4096; K = 1024; N = 4096; w = w1; wt = wt_w1;
  } else {
    tile = idx - 8192; K = 4096; N = 1024; w = w2; wt = wt_w2;
  }
  const int ntx = N >> 5;
  const int nb = (tile % ntx) * 32, kb = (tile / ntx) * 32;
  __shared__ float tilebuf[32][33];
  const int tx = threadIdx.x & 31, ty = threadIdx.x >> 5;  // 32 x 8
#pragma unroll
  for (int i = 0; i < 4; ++i)
    tilebuf[ty + i * 8][tx] = w[(size_t)(kb + ty + i * 8) * N + nb + tx];
  __syncthreads();
#pragma unroll
  for (int i = 0; i < 4; ++i)
    wt[(size_t)(nb + ty + i * 8) * K + kb + tx] = __float2bfloat16(tilebuf[tx][ty + i * 8]);
}

// ---------------------------------------------------------------------------
// LayerNorm: fp32 in -> bf16 out, one block per token (1024 ch, 256 thr x 4)
// ---------------------------------------------------------------------------
__global__ __launch_bounds__(256)
void ln_kernel(const float* __restrict__ in, const float* __restrict__ g,
               const float* __restrict__ b, __hip_bfloat16* __restrict__ out) {
  const int t = blockIdx.x, tid = threadIdx.x;
  const float4 x = *(const float4*)(in + (size_t)t * 1024 + tid * 4);
  float s = x.x + x.y + x.z + x.w;
  float sq = x.x * x.x + x.y * x.y + x.z * x.z + x.w * x.w;
#pragma unroll
  for (int off = 32; off >= 1; off >>= 1) {
    s += __shfl_down(s, off);
    sq += __shfl_down(sq, off);
  }
  __shared__ float red[8];
  const int wave = tid >> 6, lane = tid & 63;
  if (lane == 0) { red[wave] = s; red[4 + wave] = sq; }
  __syncthreads();
  s = red[0] + red[1] + red[2] + red[3];
  sq = red[4] + red[5] + red[6] + red[7];
  const float mean = s * (1.0f / 1024.0f);
  const float var = sq * (1.0f / 1024.0f) - mean * mean;
  const float rstd = rsqrtf(var + 1e-6f);
  const int c = tid * 4;
  const float4 gg = *(const float4*)(g + c);
  const float4 bb = *(const float4*)(b + c);
  ushort4 o;
  o.x = bf16bits((x.x - mean) * rstd * gg.x + bb.x);
  o.y = bf16bits((x.y - mean) * rstd * gg.y + bb.y);
  o.z = bf16bits((x.z - mean) * rstd * gg.z + bb.z);
  o.w = bf16bits((x.w - mean) * rstd * gg.w + bb.w);
  *(ushort4*)((unsigned short*)out + (size_t)t * 1024 + c) = o;
}

// ---------------------------------------------------------------------------
// GEMM: C[M,N] = A[M,K] @ Bt[N,K]^T, bf16 inputs, fp32 accum.
// 128x128 tile, BK=64, 256 threads (4 waves, 2x2 of 64x64), 16x16x32 MFMA.
// Best measured configuration (r12, 553.5us): 84 VGPR / 6-wave config;
// conflict-free granule-XOR LDS (write-side source pre-swizzle + read XOR);
// bijective XCD swizzle + column-grouped raster; gelu_fast + fences (MODE 1).
// Falsified alternatives (do not revisit): dbuf/8-phase/3-buf pipelines
// (r1-r3), LDS-repack & packed C^T epilogues (r5-r6, VGPR 88 cliff),
// launch_bounds cap (r9, non-binding), MIB=2 tiles (r13), split-K (r14).
// MODE 0: out bf16 = acc + bias
// MODE 1: out bf16 = gelu(acc + bias)
// MODE 2: out f32 += acc + bias
// MODE 3: window-unpartition row perm; out f32[t] = resid[t] + acc + bias
// ---------------------------------------------------------------------------
template<int MODE>
__global__ __launch_bounds__(256)
void gemm_bt_kernel(const __hip_bfloat16* __restrict__ A,
                    const __hip_bfloat16* __restrict__ Bt,
                    const float* __restrict__ bias,
                    void* __restrict__ out,
                    const float* __restrict__ resid,
                    int M, int N, int K) {
  __shared__ __hip_bfloat16 As[128 * 64];
  __shared__ __hip_bfloat16 Bs[128 * 64];
  const int tid = threadIdx.x;
  const int wave = tid >> 6, lane = tid & 63;
  const int lr = lane & 15, lg = lane >> 4;
  // bijective XCD swizzle (m204)
  const unsigned nwg = gridDim.x * gridDim.y;
  const unsigned bid0 = blockIdx.y * gridDim.x + blockIdx.x;
  const unsigned xcd = bid0 & 7u, idx = bid0 >> 3;
  const unsigned q8 = nwg >> 3, r8 = nwg & 7u;
  const unsigned L = (xcd < r8 ? xcd * (q8 + 1u)
                               : r8 * (q8 + 1u) + (xcd - r8) * q8) + idx;
  // column-grouped raster: groups of 8 N-tiles, row-major within a group
  const unsigned gpr = gridDim.y * 8u;          // blocks per column-group
  const unsigned grp = L / gpr, rr = L - grp * gpr;
  const int bm = (int)(rr >> 3) * 128;
  const int bn = (int)(grp * 8u + (rr & 7u)) * 128;
  const int wr = (wave >> 1) * 64, wc = (wave & 1) * 64;
  const int srow = lane >> 3;                       // 0..7 (LDS row mod 8)
  const int scol = ((lane & 7) ^ srow) * 8;         // pre-swizzled source col
  const int rsw = lr & 7;                           // read-side XOR key

  f32x4 acc[4][4] = {};

  for (int k0 = 0; k0 < K; k0 += 64) {
#pragma unroll
    for (int c = 0; c < 4; ++c) {
      const int ch = wave * 4 + c;
      gload16(A + (size_t)(bm + ch * 8 + srow) * K + k0 + scol, &As[ch * 512]);
      gload16(Bt + (size_t)(bn + ch * 8 + srow) * K + k0 + scol, &Bs[ch * 512]);
    }
    __syncthreads();
#pragma unroll
    for (int kk = 0; kk < 64; kk += 32) {
      const int kg = kk >> 3;  // granule base: 0 or 4
      bf16x8 af[4], bfr[4];
#pragma unroll
      for (int i = 0; i < 4; ++i)
        af[i] = *(const bf16x8*)&As[(wr + i * 16 + lr) * 64 + (((kg + lg) ^ rsw) * 8)];
#pragma unroll
      for (int i = 0; i < 4; ++i)
        bfr[i] = *(const bf16x8*)&Bs[(wc + i * 16 + lr) * 64 + (((kg + lg) ^ rsw) * 8)];
#pragma unroll
      for (int mi = 0; mi < 4; ++mi)
#pragma unroll
        for (int ni = 0; ni < 4; ++ni)
          acc[mi][ni] = __builtin_amdgcn_mfma_f32_16x16x32_bf16(af[mi], bfr[ni],
                                                                acc[mi][ni], 0, 0, 0);
    }
    __syncthreads();
  }

#pragma unroll
  for (int ni = 0; ni < 4; ++ni) {
    const int gn = bn + wc + ni * 16 + lr;
    const float bv = bias ? bias[gn] : 0.0f;
#pragma unroll
    for (int mi = 0; mi < 4; ++mi) {
      const int rowb = bm + wr + mi * 16 + lg * 4;
#pragma unroll
      for (int j = 0; j < 4; ++j) {
        const float v = acc[mi][ni][j] + bv;
        const int gm = rowb + j;
        if (MODE == 0) {
          ((__hip_bfloat16*)out)[(size_t)gm * N + gn] = __float2bfloat16(v);
        } else if (MODE == 1) {
          const float gl = gelu_fast(v);
          ((__hip_bfloat16*)out)[(size_t)gm * N + gn] = __float2bfloat16(gl);
          __builtin_amdgcn_sched_barrier(0);  // cap live ranges (r8 lesson)
        } else if (MODE == 2) {
          ((float*)out)[(size_t)gm * N + gn] += v;
        } else {
          const int win = gm / 576, s = gm % 576;
          const int bb2 = win / 9, wi = (win % 9) / 3, wj = win % 3;
          const int t = (bb2 * 72 + wi * 24 + (s / 24)) * 72 + wj * 24 + (s % 24);
          ((float*)out)[(size_t)t * 1024 + gn] =
              resid[(size_t)t * 1024 + gn] + v;
        }
      }
    }
  }
}

// ---------------------------------------------------------------------------
// ropev: RoPE+bias+window scatter for Q/K (blocks x<576) AND V bias+window
// gather+transpose (blocks x>=576, head = x-576) in one dispatch.
// ---------------------------------------------------------------------------
__global__ __launch_bounds__(256)
void ropev_kernel(const __hip_bfloat16* __restrict__ qkvraw,
                  const float* __restrict__ bq, const float* __restrict__ bk,
                  const float* __restrict__ bv,
                  const float* __restrict__ cost, const float* __restrict__ sint,
                  __hip_bfloat16* __restrict__ qw, __hip_bfloat16* __restrict__ kw,
                  __hip_bfloat16* __restrict__ vt) {
  __shared__ __hip_bfloat16 tile[64][72];
  const int win = blockIdx.y;  // 0..17
  const int b = win / 9, wi = (win % 9) / 3, wj = win % 3;
  const int tid = threadIdx.x;
  if (blockIdx.x < 576) {
    const int s = blockIdx.x;
    const int t = (b * 72 + wi * 24 + (s / 24)) * 72 + wj * 24 + (s % 24);
    const int col = tid * 4;           // 0..1020
    const int head = col >> 6, d = col & 63;
    const float c0 = cost[s * 64 + d + 0], c1 = cost[s * 64 + d + 1];
    const float c2 = cost[s * 64 + d + 2], c3 = cost[s * 64 + d + 3];
    const float s0 = sint[s * 64 + d + 0], s1 = sint[s * 64 + d + 1];
    const float s2 = sint[s * 64 + d + 2], s3 = sint[s * 64 + d + 3];
    const size_t rbase = (size_t)t * 3072;
    const size_t obase = (((size_t)(win * 16 + head)) * 576 + s) * 64 + d;
    {  // Q (fold softmax scale 1/8)
      const float q0 = __bfloat162float(qkvraw[rbase + col + 0]) + bq[col + 0];
      const float q1 = __bfloat162float(qkvraw[rbase + col + 1]) + bq[col + 1];
      const float q2 = __bfloat162float(qkvraw[rbase + col + 2]) + bq[col + 2];
      const float q3 = __bfloat162float(qkvraw[rbase + col + 3]) + bq[col + 3];
      ushort4 o;
      o.x = bf16bits(0.125f * (q0 * c0 - q1 * s0));
      o.y = bf16bits(0.125f * (q1 * c1 + q0 * s1));
      o.z = bf16bits(0.125f * (q2 * c2 - q3 * s2));
      o.w = bf16bits(0.125f * (q3 * c3 + q2 * s3));
      *(ushort4*)((unsigned short*)qw + obase) = o;
    }
    {  // K
      const float k0 = __bfloat162float(qkvraw[rbase + 1024 + col + 0]) + bk[col + 0];
      const float k1 = __bfloat162float(qkvraw[rbase + 1024 + col + 1]) + bk[col + 1];
      const float k2 = __bfloat162float(qkvraw[rbase + 1024 + col + 2]) + bk[col + 2];
      const float k3 = __bfloat162float(qkvraw[rbase + 1024 + col + 3]) + bk[col + 3];
      ushort4 o;
      o.x = bf16bits(k0 * c0 - k1 * s0);
      o.y = bf16bits(k1 * c1 + k0 * s1);
      o.z = bf16bits(k2 * c2 - k3 * s2);
      o.w = bf16bits(k3 * c3 + k2 * s3);
      *(ushort4*)((unsigned short*)kw + obase) = o;
    }
    return;
  }
  // V: bias + gather + transpose -> vt[win][head][d][s]
  const int head = blockIdx.x - 576;
  for (int s0 = 0; s0 < 576; s0 += 64) {
#pragma unroll
    for (int rep = 0; rep < 16; ++rep) {
      const int e = rep * 256 + tid;  // 0..4095
      const int si = e >> 6, d = e & 63;
      const int s = s0 + si;
      const int t = (b * 72 + wi * 24 + (s / 24)) * 72 + wj * 24 + (s % 24);
      const float v = __bfloat162float(qkvraw[(size_t)t * 3072 + 2048 + head * 64 + d])
                    + bv[head * 64 + d];
      tile[d][si] = __float2bfloat16(v);
    }
    __syncthreads();
#pragma unroll
    for (int rep = 0; rep < 16; ++rep) {
      const int e = rep * 256 + tid;
      const int d = e >> 6, si = e & 63;
      vt[((size_t)(win * 16 + head) * 64 + d) * 576 + s0 + si] = tile[d][si];
    }
    __syncthreads();
  }
}

// ---------------------------------------------------------------------------
// Flash attention per (qtile, head, win). 256 thr = 4 waves, 16 q-rows/wave.
// K/V LDS + Plds round-trip granule-XOR swizzled; T13 defer-max; setprio
// around MFMA clusters. (r12 form, best measured.)
// ---------------------------------------------------------------------------
__global__ __launch_bounds__(256)
void attn_kernel(const __hip_bfloat16* __restrict__ qw,
                 const __hip_bfloat16* __restrict__ kw,
                 const __hip_bfloat16* __restrict__ vt,
                 __hip_bfloat16* __restrict__ ow) {
  __shared__ __hip_bfloat16 Klds[2][64 * 64];
  __shared__ __hip_bfloat16 Vlds[2][64 * 64];
  __shared__ __hip_bfloat16 Plds[4 * 16 * 64];
  const unsigned nwg = gridDim.x * gridDim.y * gridDim.z;
  const unsigned bid0 = (blockIdx.z * gridDim.y + blockIdx.y) * gridDim.x + blockIdx.x;
  const unsigned Lw = (bid0 & 7u) * (nwg >> 3) + (bid0 >> 3);
  const int qt = (int)(Lw % 9u);          // 0..8
  const unsigned r = Lw / 9u;
  const int head = (int)(r & 15u);        // 0..15
  const int win = (int)(r >> 4);          // 0..17
  const int bh = win * 16 + head;
  const int tid = threadIdx.x, wave = tid >> 6, lane = tid & 63;
  const int lr = lane & 15, lg = lane >> 4;
  const int rsw = lr & 7;

  const int qrow = qt * 64 + wave * 16 + lr;
  const __hip_bfloat16* qbase = qw + ((size_t)bh * 576 + qrow) * 64;
  const bf16x8 q0 = *(const bf16x8*)(qbase + lg * 8);
  const bf16x8 q1 = *(const bf16x8*)(qbase + 32 + lg * 8);

  f32x4 oacc[4] = {};
  float mrow[4] = {-1e30f, -1e30f, -1e30f, -1e30f};
  float lrow[4] = {};

  const int srow = lane >> 3;
  const int sw = ((lane & 7) ^ srow) * 8;  // pre-swizzled source col

  auto stagekv = [&](int buf, int kv) {
#pragma unroll
    for (int c = 0; c < 2; ++c) {
      const int ch = wave * 2 + c;
      gload16(kw + ((size_t)bh * 576 + kv * 64 + ch * 8 + srow) * 64 + sw,
              &Klds[buf][ch * 512]);
      gload16(vt + ((size_t)bh * 64 + ch * 8 + srow) * 576 + kv * 64 + sw,
              &Vlds[buf][ch * 512]);
    }
  };

  stagekv(0, 0);
  __syncthreads();

  for (int kv = 0; kv < 9; ++kv) {
    const int cur = kv & 1;
    if (kv + 1 < 9) stagekv(cur ^ 1, kv + 1);
    __builtin_amdgcn_sched_barrier(0);

    f32x4 sfr[4];
    __builtin_amdgcn_s_setprio(1);
#pragma unroll
    for (int c = 0; c < 4; ++c) {
      const bf16x8 b0 = *(const bf16x8*)&Klds[cur][(c * 16 + lr) * 64 + ((lg ^ rsw) * 8)];
      const bf16x8 b1 = *(const bf16x8*)&Klds[cur][(c * 16 + lr) * 64 + (((4 + lg) ^ rsw) * 8)];
      f32x4 z = {};
      z = __builtin_amdgcn_mfma_f32_16x16x32_bf16(q0, b0, z, 0, 0, 0);
      z = __builtin_amdgcn_mfma_f32_16x16x32_bf16(q1, b1, z, 0, 0, 0);
      sfr[c] = z;
    }
    __builtin_amdgcn_s_setprio(0);

    // tile-max per row
    float mjv[4];
#pragma unroll
    for (int j = 0; j < 4; ++j) {
      float mj = fmaxf(fmaxf(sfr[0][j], sfr[1][j]), fmaxf(sfr[2][j], sfr[3][j]));
#pragma unroll
      for (int off = 1; off < 16; off <<= 1) mj = fmaxf(mj, __shfl_xor(mj, off));
      mjv[j] = mj;
    }
    // T13 defer-max: rescale only if some row grew past threshold
    bool defer = true;
#pragma unroll
    for (int j = 0; j < 4; ++j) defer = defer && (mjv[j] <= mrow[j] + 8.0f);
    if (!__all(defer)) {
#pragma unroll
      for (int j = 0; j < 4; ++j) {
        const float mn = fmaxf(mrow[j], mjv[j]);
        const float rs = __expf(mrow[j] - mn);
        mrow[j] = mn;
        lrow[j] *= rs;
#pragma unroll
        for (int d = 0; d < 4; ++d) oacc[d][j] *= rs;
      }
    }
    float p[4][4];
#pragma unroll
    for (int j = 0; j < 4; ++j) {
      float rs = 0.0f;
#pragma unroll
      for (int c = 0; c < 4; ++c) {
        const float pp = __expf(sfr[c][j] - mrow[j]);
        p[c][j] = pp;
        rs += pp;
      }
#pragma unroll
      for (int off = 1; off < 16; off <<= 1) rs += __shfl_xor(rs, off);
      lrow[j] += rs;
    }

    // P store (granule-XOR swizzled)
    {
      const int g0 = lr >> 3, c3 = lr & 7;
#pragma unroll
      for (int c = 0; c < 4; ++c)
#pragma unroll
        for (int j = 0; j < 4; ++j) {
          const int row = lg * 4 + j;
          const int g = (c * 2 + g0) ^ (row & 7);
          Plds[wave * 1024 + row * 64 + g * 8 + c3] = __float2bfloat16(p[c][j]);
        }
    }

    const bf16x8 pa0 = *(const bf16x8*)&Plds[wave * 1024 + lr * 64 + ((lg ^ rsw) * 8)];
    const bf16x8 pa1 = *(const bf16x8*)&Plds[wave * 1024 + lr * 64 + (((4 + lg) ^ rsw) * 8)];
    __builtin_amdgcn_s_setprio(1);
#pragma unroll
    for (int d = 0; d < 4; ++d) {
      const bf16x8 v0 = *(const bf16x8*)&Vlds[cur][(d * 16 + lr) * 64 + ((lg ^ rsw) * 8)];
      const bf16x8 v1 = *(const bf16x8*)&Vlds[cur][(d * 16 + lr) * 64 + (((4 + lg) ^ rsw) * 8)];
      oacc[d] = __builtin_amdgcn_mfma_f32_16x16x32_bf16(pa0, v0, oacc[d], 0, 0, 0);
      oacc[d] = __builtin_amdgcn_mfma_f32_16x16x32_bf16(pa1, v1, oacc[d], 0, 0, 0);
    }
    __builtin_amdgcn_s_setprio(0);
    __syncthreads();
  }

#pragma unroll
  for (int j = 0; j < 4; ++j) {
    const float inv = 1.0f / lrow[j];
    const int srow2 = qt * 64 + wave * 16 + lg * 4 + j;
    const size_t base = ((size_t)win * 576 + srow2) * 1024 + head * 64;
#pragma unroll
    for (int d = 0; d < 4; ++d)
      ow[base + d * 16 + lr] = __float2bfloat16(oacc[d][j] * inv);
  }
}

// ---------------------------------------------------------------------------
extern "C" void kernel_launch(void* const* d_in, const int* in_sizes, int n_in,
                              void* d_out, int out_size, void* d_ws, size_t ws_size,
                              hipStream_t stream) {
  const float* hidden = (const float*)d_in[0];
  const float* ln1_g = (const float*)d_in[1];
  const float* ln1_b = (const float*)d_in[2];
  const float* wq = (const float*)d_in[3];
  const float* bq = (const float*)d_in[4];
  const float* wk = (const float*)d_in[5];
  const float* bk = (const float*)d_in[6];
  const float* wv = (const float*)d_in[7];
  const float* bv = (const float*)d_in[8];
  const float* wo = (const float*)d_in[9];
  const float* bo = (const float*)d_in[10];
  const float* ln2_g = (const float*)d_in[11];
  const float* ln2_b = (const float*)d_in[12];
  const float* w1 = (const float*)d_in[13];
  const float* b1 = (const float*)d_in[14];
  const float* w2 = (const float*)d_in[15];
  const float* b2 = (const float*)d_in[16];
  float* out = (float*)d_out;

  char* p = (char*)d_ws;
  auto alloc = [&](size_t bytes) {
    char* r = p;
    p += (bytes + 255) & ~(size_t)255;
    return r;
  };
  __hip_bfloat16* wt_qkv = (__hip_bfloat16*)alloc(3072ull * 1024 * 2);
  __hip_bfloat16* wt_wo  = (__hip_bfloat16*)alloc(1024ull * 1024 * 2);
  __hip_bfloat16* wt_w1  = (__hip_bfloat16*)alloc(4096ull * 1024 * 2);
  __hip_bfloat16* wt_w2  = (__hip_bfloat16*)alloc(1024ull * 4096 * 2);
  float* cost = (float*)alloc(576ull * 64 * 4);
  float* sint = (float*)alloc(576ull * 64 * 4);
  __hip_bfloat16* xbuf = (__hip_bfloat16*)alloc(10368ull * 1024 * 2);  // xln / o_w / xln2
  char* big = alloc(10368ull * 4096 * 2);                              // qkvraw+qw | h1
  __hip_bfloat16* qkvraw = (__hip_bfloat16*)big;
  __hip_bfloat16* qw = (__hip_bfloat16*)(big + 10368ull * 3072 * 2);
  __hip_bfloat16* h1 = (__hip_bfloat16*)big;
  __hip_bfloat16* kw = (__hip_bfloat16*)alloc(18ull * 16 * 576 * 64 * 2);
  __hip_bfloat16* vt = (__hip_bfloat16*)alloc(18ull * 16 * 64 * 576 * 2);

  // weights -> bf16 transposed + RoPE tables (ONE dispatch)
  prep_kernel<<<12432, 256, 0, stream>>>(wq, wk, wv, wo, w1, w2,
                                         wt_qkv, wt_wo, wt_w1, wt_w2, cost, sint);
  // LN1 -> xln (bf16)
  ln_kernel<<<10368, 256, 0, stream>>>(hidden, ln1_g, ln1_b, xbuf);
  // QKV fused GEMM: [10368,1024] x [3072,1024]^T -> qkvraw bf16
  gemm_bt_kernel<0><<<dim3(24, 81), 256, 0, stream>>>(
      xbuf, wt_qkv, nullptr, qkvraw, nullptr, 10368, 3072, 1024);
  // RoPE + window scatter (Q,K) and V transpose (ONE dispatch)
  ropev_kernel<<<dim3(592, 18), 256, 0, stream>>>(
      qkvraw, bq, bk, bv, cost, sint, qw, kw, vt);
  // attention -> o_w (windowed rows, [tw][1024]) into xbuf
  attn_kernel<<<dim3(9, 16, 18), 256, 0, stream>>>(qw, kw, vt, xbuf);
  // Wo GEMM + bias + residual + window-unpartition -> d_out (fp32 x)
  gemm_bt_kernel<3><<<dim3(8, 81), 256, 0, stream>>>(
      xbuf, wt_wo, bo, out, hidden, 10368, 1024, 1024);
  // LN2 -> xln2 (bf16)
  ln_kernel<<<10368, 256, 0, stream>>>(out, ln2_g, ln2_b, xbuf);
  // MLP up + GELU -> h1 bf16
  gemm_bt_kernel<1><<<dim3(32, 81), 256, 0, stream>>>(
      xbuf, wt_w1, b1, h1, nullptr, 10368, 4096, 1024);
  // MLP down, += into d_out
  gemm_bt_kernel<2><<<dim3(8, 81), 256, 0, stream>>>(
      h1, wt_w2, b2, out, nullptr, 10368, 1024, 4096);
}